// Round 1
// baseline (142.116 us; speedup 1.0000x reference)
//
#include <hip/hip_runtime.h>

// Row-wise dot product: out[n] = sum_d x[n][d] * y[n][d]
// N = 16384 rows, D = 1024 cols, fp32 in / fp32 out.
//
// R4: plain (cacheable) loads + 4 rows per wave.
// Evidence from R3 rocprof: rowdot is NOT in the top-5 dispatches -> it runs
// in <40.2us; the graded 135us is dominated by harness 256MiB poison fills
// (40us each @ 6.6 TB/s write). Kernel-side headroom is at most
// (rowdot - 20.6us roofline). This round tests the last two plausible causes
// of the claimed 3.1 TB/s read pin:
//   (a) nontemporal hint bypassing the 256MiB L3 (inputs = 134MB, L3-fittable)
//   (b) per-wave tail overhead (now amortized over 4 rows, 32 loads in flight)
// If dur_us is unchanged, the kernel is memory-roofline-bound and the graded
// time is fill-dominated -> ROOFLINE.

#define D 1024

typedef float v4f __attribute__((ext_vector_type(4)));

__device__ __forceinline__ float dot4(v4f a, v4f b) {
    return a.x * b.x + a.y * b.y + a.z * b.z + a.w * b.w;
}

__global__ __launch_bounds__(256) void rowdot_kernel(const float* __restrict__ x,
                                                     const float* __restrict__ y,
                                                     float* __restrict__ out) {
    const int wave = threadIdx.x >> 6;
    const int lane = threadIdx.x & 63;
    const int w = blockIdx.x * 4 + wave;  // global wave id
    const int r0 = w * 4;                 // four consecutive rows per wave

    // Row stride in v4f units: D/4 = 256. Each row is 4 chunks of 64 lanes.
    const v4f* __restrict__ xp = (const v4f*)(x + (size_t)r0 * D);
    const v4f* __restrict__ yp = (const v4f*)(y + (size_t)r0 * D);

    // 32 independent 16B loads per lane (128 payload VGPRs), all issued
    // before the barrier below. Fully-unrolled constant indices keep the
    // arrays in registers (no scratch).
    v4f ax[4][4];
    v4f ay[4][4];
#pragma unroll
    for (int i = 0; i < 4; ++i) {
#pragma unroll
        for (int j = 0; j < 4; ++j) {
            ax[i][j] = xp[i * 256 + j * 64 + lane];
            ay[i][j] = yp[i * 256 + j * 64 + lane];
        }
    }

    // Compiler barrier: pin all 32 loads before any consumption; s_waitcnt
    // then drains progressively in issue order as the FMAs consume them.
    asm volatile("" ::: "memory");

    float s0 = 0.0f, s1 = 0.0f, s2 = 0.0f, s3 = 0.0f;
#pragma unroll
    for (int j = 0; j < 4; ++j) {
        s0 += dot4(ax[0][j], ay[0][j]);
        s1 += dot4(ax[1][j], ay[1][j]);
        s2 += dot4(ax[2][j], ay[2][j]);
        s3 += dot4(ax[3][j], ay[3][j]);
    }

    // four interleaved wave-64 reduction chains
#pragma unroll
    for (int off = 32; off > 0; off >>= 1) {
        s0 += __shfl_down(s0, off, 64);
        s1 += __shfl_down(s1, off, 64);
        s2 += __shfl_down(s2, off, 64);
        s3 += __shfl_down(s3, off, 64);
    }

    if (lane == 0) {
        // r0 is a multiple of 4 -> 16B-aligned float4 store
        *(float4*)(out + r0) = make_float4(s0, s1, s2, s3);
    }
}

extern "C" void kernel_launch(void* const* d_in, const int* in_sizes, int n_in,
                              void* d_out, int out_size, void* d_ws, size_t ws_size,
                              hipStream_t stream) {
    const float* x = (const float*)d_in[0];
    const float* y = (const float*)d_in[1];
    float* out = (float*)d_out;
    const int N = out_size;  // 16384 rows

    // 4 rows per wave, 4 waves per block -> 16 rows per block
    rowdot_kernel<<<N / 16, 256, 0, stream>>>(x, y, out);
}

// Round 2
// 134.024 us; speedup vs baseline: 1.0604x; 1.0604x over previous
//
#include <hip/hip_runtime.h>

// Row-wise dot product: out[n] = sum_d x[n][d] * y[n][d]
// N = 16384 rows, D = 1024 cols, fp32 in / fp32 out.
//
// R5: restore the measured-best R3 structure (regression revert).
// Evidence ledger:
//  - R4 (plain loads, 1024 blocks): rowdot 45.2-46.4us, VALUBusy 2.8%,
//    and crucially dispatch 190 ran 45.7us with hbm_bytes=66KB (inputs
//    fully L3-resident) == same time as the 67MB-HBM dispatch. The kernel
//    is NOT HBM-bound, NOT VALU-bound, NOT MLP-bound; demand-read BW pins
//    at ~2.96 TB/s regardless of data source.
//  - Harness poison fills sustain 6.6 TB/s PURE WRITE on the same chip.
//  - m13 "6.29 TB/s float4 copy" decomposes as ~3.15 read + ~3.15 write.
//  - Previous session R0-R2: ~3.1 TB/s read across structures; R3
//    (NT + 2048 blocks + 16-deep clustered loads) was the best at
//    <40.2us (~3.35+ TB/s demand read) -> best observed read rate.
// Conclusion: streaming-READ path ceiling on this part is ~3.1-3.4 TB/s,
// upstream of the XCDs (L3-hit and HBM-sourced rates do not add).
// This kernel restores the configuration that achieved the best read rate:
// 2 rows/wave, 4 waves/block, grid=N/8=2048 blocks (32 waves/CU, 100%
// occupancy), 16 independent nontemporal 16B loads clustered before a
// compiler barrier. Graded time = kernel + ~96.5us fixed harness fills.

#define D 1024

typedef float v4f __attribute__((ext_vector_type(4)));

__global__ __launch_bounds__(256) void rowdot_kernel(const float* __restrict__ x,
                                                     const float* __restrict__ y,
                                                     float* __restrict__ out) {
    const int wave = threadIdx.x >> 6;
    const int lane = threadIdx.x & 63;
    const int w = blockIdx.x * 4 + wave;  // global wave id
    const int r0 = w * 2;                 // two consecutive rows per wave

    const v4f* __restrict__ x0 = (const v4f*)(x + (size_t)r0 * D);
    const v4f* __restrict__ y0 = (const v4f*)(y + (size_t)r0 * D);
    const v4f* __restrict__ x1 = (const v4f*)(x + (size_t)(r0 + 1) * D);
    const v4f* __restrict__ y1 = (const v4f*)(y + (size_t)(r0 + 1) * D);

    // 16 independent loads, pinned before any use by the barrier below.
    v4f a0 = __builtin_nontemporal_load(&x0[lane]);
    v4f a1 = __builtin_nontemporal_load(&x0[lane + 64]);
    v4f a2 = __builtin_nontemporal_load(&x0[lane + 128]);
    v4f a3 = __builtin_nontemporal_load(&x0[lane + 192]);
    v4f b0 = __builtin_nontemporal_load(&y0[lane]);
    v4f b1 = __builtin_nontemporal_load(&y0[lane + 64]);
    v4f b2 = __builtin_nontemporal_load(&y0[lane + 128]);
    v4f b3 = __builtin_nontemporal_load(&y0[lane + 192]);
    v4f c0 = __builtin_nontemporal_load(&x1[lane]);
    v4f c1 = __builtin_nontemporal_load(&x1[lane + 64]);
    v4f c2 = __builtin_nontemporal_load(&x1[lane + 128]);
    v4f c3 = __builtin_nontemporal_load(&x1[lane + 192]);
    v4f d0 = __builtin_nontemporal_load(&y1[lane]);
    v4f d1 = __builtin_nontemporal_load(&y1[lane + 64]);
    v4f d2 = __builtin_nontemporal_load(&y1[lane + 128]);
    v4f d3 = __builtin_nontemporal_load(&y1[lane + 192]);

    // Compiler barrier: all 16 loads must be issued before anything below.
    asm volatile("" ::: "memory");

    float s0 = 0.0f, s1 = 0.0f;
    s0 += a0.x * b0.x + a0.y * b0.y + a0.z * b0.z + a0.w * b0.w;
    s0 += a1.x * b1.x + a1.y * b1.y + a1.z * b1.z + a1.w * b1.w;
    s0 += a2.x * b2.x + a2.y * b2.y + a2.z * b2.z + a2.w * b2.w;
    s0 += a3.x * b3.x + a3.y * b3.y + a3.z * b3.z + a3.w * b3.w;
    s1 += c0.x * d0.x + c0.y * d0.y + c0.z * d0.z + c0.w * d0.w;
    s1 += c1.x * d1.x + c1.y * d1.y + c1.z * d1.z + c1.w * d1.w;
    s1 += c2.x * d2.x + c2.y * d2.y + c2.z * d2.z + c2.w * d2.w;
    s1 += c3.x * d3.x + c3.y * d3.y + c3.z * d3.z + c3.w * d3.w;

    // two interleaved wave-64 reduction chains
    #pragma unroll
    for (int off = 32; off > 0; off >>= 1) {
        s0 += __shfl_down(s0, off, 64);
        s1 += __shfl_down(s1, off, 64);
    }

    if (lane == 0) {
        *(float2*)(out + r0) = make_float2(s0, s1);
    }
}

extern "C" void kernel_launch(void* const* d_in, const int* in_sizes, int n_in,
                              void* d_out, int out_size, void* d_ws, size_t ws_size,
                              hipStream_t stream) {
    const float* x = (const float*)d_in[0];
    const float* y = (const float*)d_in[1];
    float* out = (float*)d_out;
    const int N = out_size;  // 16384 rows

    // 2 rows per wave, 4 waves per block -> 8 rows per block
    // grid = 2048 blocks = 8 blocks/CU = 32 waves/CU (full occupancy)
    rowdot_kernel<<<N / 8, 256, 0, stream>>>(x, y, out);
}